// Round 12
// baseline (227.646 us; speedup 1.0000x reference)
//
#include <hip/hip_runtime.h>

typedef unsigned short u16;
typedef __bf16 bf16x8 __attribute__((ext_vector_type(8)));
typedef float f32x4 __attribute__((ext_vector_type(4)));

__device__ inline float bf2f(u16 u) {
    unsigned int x = ((unsigned int)u) << 16;
    return __builtin_bit_cast(float, x);
}
__device__ inline u16 f2bf(float f) {
    unsigned int x = __builtin_bit_cast(unsigned int, f);
    return (u16)((x + 0x7FFFu + ((x >> 16) & 1u)) >> 16);
}
__device__ inline float sigm(float v) { return 1.f / (1.f + __expf(-v)); }
// 2^x via v_exp_f32 (ISA: D = 2^S0). Callers pre-fold log2e into the operand.
__device__ inline float ex2(float x) {
    float r; asm("v_exp_f32 %0, %1" : "=v"(r) : "v"(x)); return r;
}

__device__ __forceinline__ void gload16(const void* g, void* l) {
    __builtin_amdgcn_global_load_lds(
        (const __attribute__((address_space(1))) void*)g,
        (__attribute__((address_space(3))) void*)l, 16, 0, 0);
}

__device__ inline uint4 pack8(const float* p) {
    const float4* q = (const float4*)p;
    float4 a = q[0], b = q[1];
    union { u16 h[8]; uint4 v; } u;
    u.h[0] = f2bf(a.x); u.h[1] = f2bf(a.y); u.h[2] = f2bf(a.z); u.h[3] = f2bf(a.w);
    u.h[4] = f2bf(b.x); u.h[5] = f2bf(b.y); u.h[6] = f2bf(b.z); u.h[7] = f2bf(b.w);
    return u.v;
}

// ---------------------------------------------------------------------------
// Merged front conversions: x (1024 blk) | in_w (2048) | xproj pad (128) |
// dtw (64) | out_proj w (1024, parked in d_out) | conv_w transpose (32).
// ---------------------------------------------------------------------------
__global__ __launch_bounds__(256)
void cvt_front(const float* __restrict__ x, const float* __restrict__ inw,
               const float* __restrict__ xpw, const float* __restrict__ convw,
               const float* __restrict__ dtw, const float* __restrict__ opw,
               u16* __restrict__ x_bf, u16* __restrict__ inw_bf,
               u16* __restrict__ xpw_bf, float* __restrict__ wt,
               u16* __restrict__ dtw_bf, u16* __restrict__ opw_bf)
{
    int bk = blockIdx.x, tid = threadIdx.x;
    if (bk < 1024) {
        int i = bk * 256 + tid;
        ((uint4*)x_bf)[i] = pack8(x + (size_t)i * 8);
    } else if (bk < 3072) {
        int i = (bk - 1024) * 256 + tid;
        ((uint4*)inw_bf)[i] = pack8(inw + (size_t)i * 8);
    } else if (bk < 3200) {
        int i = (bk - 3072) * 256 + tid;
        int row = (i * 8) >> 11;
        ((uint4*)xpw_bf)[i] = (row < 96) ? pack8(xpw + (size_t)row * 2048 + ((i * 8) & 2047))
                                         : make_uint4(0u, 0u, 0u, 0u);
    } else if (bk < 3264) {
        int i = (bk - 3200) * 256 + tid;   // < 16384 (131072 elems / 8)
        ((uint4*)dtw_bf)[i] = pack8(dtw + (size_t)i * 8);
    } else if (bk < 4288) {
        int i = (bk - 3264) * 256 + tid;   // < 262144 (2M elems / 8)
        ((uint4*)opw_bf)[i] = pack8(opw + (size_t)i * 8);
    } else {
        int i = (bk - 4288) * 256 + tid;   // < 8192
        wt[(i & 3) * 2048 + (i >> 2)] = convw[i];
    }
}

// ---------------------------------------------------------------------------
// MFMA NT GEMM, 128x128 tile, BK=64, gload_lds w16 + XOR-swizzle, XCD swizzle.
// For out_proj (r10: BM=64 doubles B-panel re-reads, ~+10us there).
// EPI: 0 none; 1 softplus(acc+bias[col]); 2 silu on cols>=2048.
// ---------------------------------------------------------------------------
template<int EPI, bool OUTF32>
__global__ __launch_bounds__(256, 4)
void gemm2(const u16* __restrict__ A, int lda,
           const u16* __restrict__ B, int ldb,
           void* __restrict__ Cout, int ldc,
           int N, int ksplit, size_t zElems,
           const float* __restrict__ bias)
{
    __shared__ u16 sA[128][64];
    __shared__ u16 sB[128][64];

    const int tid  = threadIdx.x;
    const int lane = tid & 63;
    const int wave = tid >> 6;

    int nxy = gridDim.x * gridDim.y;
    int id  = blockIdx.y * gridDim.x + blockIdx.x;
    int bx, by;
    if ((nxy & 7) == 0) {
        int cpx = nxy >> 3;
        int swz = (id & 7) * cpx + (id >> 3);
        bx = swz % gridDim.x;
        by = swz / gridDim.x;
    } else { bx = blockIdx.x; by = blockIdx.y; }

    const int wm = (wave >> 1) * 64;
    const int wn = (wave & 1) * 64;
    const int m0 = by * 128;
    const int n0 = bx * 128;
    const int lm = lane & 15;
    const int g  = lane >> 4;
    const int k0 = blockIdx.z * ksplit;

    const int rr = lane >> 3;
    const int sl = lane & 7;
    const int xsl = sl ^ rr;
    const u16* gA = A + (size_t)(m0 + wave * 8 + rr) * lda + k0 + xsl * 8;
    const u16* gB = B + (size_t)(n0 + wave * 8 + rr) * ldb + k0 + xsl * 8;
    const int ldsRow = (wave * 8) * 128;

    f32x4 acc[4][4] = {};

    for (int kb = 0; kb < ksplit; kb += 64) {
        #pragma unroll
        for (int c = 0; c < 4; ++c) {
            gload16(gA + (size_t)c * 32 * lda + kb, (char*)sA + c * 4096 + ldsRow);
            gload16(gB + (size_t)c * 32 * ldb + kb, (char*)sB + c * 4096 + ldsRow);
        }
        __syncthreads();

        bf16x8 af[2][4], bfr[2][4];
        #pragma unroll
        for (int h = 0; h < 2; ++h) {
            #pragma unroll
            for (int i = 0; i < 4; ++i) {
                int ra = wm + i * 16 + lm;
                int rb = wn + i * 16 + lm;
                int chunk = (((h << 2) | g) ^ (lm & 7)) << 4;
                af[h][i]  = *(const bf16x8*)((const char*)sA + ra * 128 + chunk);
                bfr[h][i] = *(const bf16x8*)((const char*)sB + rb * 128 + chunk);
            }
        }
        #pragma unroll
        for (int h = 0; h < 2; ++h)
            #pragma unroll
            for (int i = 0; i < 4; ++i)
                #pragma unroll
                for (int j = 0; j < 4; ++j)
                    acc[i][j] = __builtin_amdgcn_mfma_f32_16x16x32_bf16(af[h][i], bfr[h][j], acc[i][j], 0, 0, 0);
        __syncthreads();
    }

    #pragma unroll
    for (int i = 0; i < 4; ++i) {
        int crow = m0 + wm + i * 16 + ((lane >> 4) << 2);
        #pragma unroll
        for (int j = 0; j < 4; ++j) {
            int ccol = n0 + wn + j * 16 + lm;
            if (ccol < N) {
                #pragma unroll
                for (int r = 0; r < 4; ++r) {
                    float v = acc[i][j][r];
                    if (EPI == 1) { v += bias[ccol]; v = (v > 20.f) ? v : log1pf(__expf(v)); }
                    if (EPI == 2 && ccol >= 2048) v *= sigm(v);
                    size_t off = (size_t)blockIdx.z * zElems + (size_t)(crow + r) * ldc + ccol;
                    if (OUTF32) ((float*)Cout)[off] = v;
                    else        ((u16*)Cout)[off]   = f2bf(v);
                }
            }
        }
    }
}

// ---------------------------------------------------------------------------
// MFMA NT GEMM, 64x128 tile, BK=64, 2-PHASE DOUBLE-BUFFERED (T3 minimum):
// one barrier per K-iter; next-tile gload_lds issued before ds_read+MFMA of
// the current buffer, so staging flies under compute instead of being
// drained immediately. 48 KB LDS -> 3 blocks/CU (12 waves). For in_proj.
// ---------------------------------------------------------------------------
template<int EPI, bool OUTF32>
__global__ __launch_bounds__(256, 3)
void gemm_w(const u16* __restrict__ A, int lda,
            const u16* __restrict__ B, int ldb,
            void* __restrict__ Cout, int ldc,
            int N, int ksplit, size_t zElems,
            const float* __restrict__ bias)
{
    __shared__ u16 sA[2][64][64];    // 16 KB
    __shared__ u16 sB[2][128][64];   // 32 KB

    const int tid  = threadIdx.x;
    const int lane = tid & 63;
    const int wave = tid >> 6;

    int nxy = gridDim.x * gridDim.y;
    int id  = blockIdx.y * gridDim.x + blockIdx.x;
    int bx, by;
    if ((nxy & 7) == 0) {
        int cpx = nxy >> 3;
        int swz = (id & 7) * cpx + (id >> 3);
        bx = swz % gridDim.x;
        by = swz / gridDim.x;
    } else { bx = blockIdx.x; by = blockIdx.y; }

    const int wm = (wave >> 1) * 32;     // rows: 2 wave-rows of 32
    const int wn = (wave & 1) * 64;      // cols: 2 wave-cols of 64
    const int m0 = by * 64;
    const int n0 = bx * 128;
    const int lm = lane & 15;
    const int g  = lane >> 4;
    const int k0 = blockIdx.z * ksplit;

    const int rr = lane >> 3;
    const int sl = lane & 7;
    const int xsl = sl ^ rr;
    const u16* gA = A + (size_t)(m0 + wave * 8 + rr) * lda + k0 + xsl * 8;
    const u16* gB = B + (size_t)(n0 + wave * 8 + rr) * ldb + k0 + xsl * 8;
    const int ldsRow = (wave * 8) * 128;

    f32x4 acc[2][4] = {};

    // prologue: stage tile 0 into buffer 0
    {
        #pragma unroll
        for (int c = 0; c < 2; ++c)
            gload16(gA + (size_t)c * 32 * lda, (char*)sA[0] + c * 4096 + ldsRow);
        #pragma unroll
        for (int c = 0; c < 4; ++c)
            gload16(gB + (size_t)c * 32 * ldb, (char*)sB[0] + c * 4096 + ldsRow);
    }

    int cur = 0;
    for (int kb = 0; kb < ksplit; kb += 64) {
        // drains this wave's vmcnt(0) then syncs: buf[cur] staged everywhere,
        // and all reads of buf[cur^1] from the previous iter are complete.
        __syncthreads();
        if (kb + 64 < ksplit) {
            #pragma unroll
            for (int c = 0; c < 2; ++c)
                gload16(gA + (size_t)c * 32 * lda + kb + 64, (char*)sA[cur ^ 1] + c * 4096 + ldsRow);
            #pragma unroll
            for (int c = 0; c < 4; ++c)
                gload16(gB + (size_t)c * 32 * ldb + kb + 64, (char*)sB[cur ^ 1] + c * 4096 + ldsRow);
        }

        const char* bA = (const char*)sA[cur];
        const char* bB = (const char*)sB[cur];
        bf16x8 af[2][2], bfr[2][4];
        #pragma unroll
        for (int h = 0; h < 2; ++h) {
            int chunk = (((h << 2) | g) ^ (lm & 7)) << 4;
            #pragma unroll
            for (int i = 0; i < 2; ++i)
                af[h][i]  = *(const bf16x8*)(bA + (wm + i * 16 + lm) * 128 + chunk);
            #pragma unroll
            for (int j = 0; j < 4; ++j)
                bfr[h][j] = *(const bf16x8*)(bB + (wn + j * 16 + lm) * 128 + chunk);
        }
        #pragma unroll
        for (int h = 0; h < 2; ++h)
            #pragma unroll
            for (int i = 0; i < 2; ++i)
                #pragma unroll
                for (int j = 0; j < 4; ++j)
                    acc[i][j] = __builtin_amdgcn_mfma_f32_16x16x32_bf16(af[h][i], bfr[h][j], acc[i][j], 0, 0, 0);
        cur ^= 1;
    }

    #pragma unroll
    for (int i = 0; i < 2; ++i) {
        int crow = m0 + wm + i * 16 + ((lane >> 4) << 2);
        #pragma unroll
        for (int j = 0; j < 4; ++j) {
            int ccol = n0 + wn + j * 16 + lm;
            if (ccol < N) {
                #pragma unroll
                for (int r = 0; r < 4; ++r) {
                    float v = acc[i][j][r];
                    if (EPI == 1) { v += bias[ccol]; v = (v > 20.f) ? v : log1pf(__expf(v)); }
                    if (EPI == 2 && ccol >= 2048) v *= sigm(v);
                    size_t off = (size_t)blockIdx.z * zElems + (size_t)(crow + r) * ldc + ccol;
                    if (OUTF32) ((float*)Cout)[off] = v;
                    else        ((u16*)Cout)[off]   = f2bf(v);
                }
            }
        }
    }
}

// ---------------------------------------------------------------------------
// MFMA NT GEMM, 64x64 tile, 16 KB LDS, 4 blocks/CU (16 waves/CU).
// For small/latency-bound shapes (dt K=64, x_proj).
// ---------------------------------------------------------------------------
template<int EPI, bool OUTF32>
__global__ __launch_bounds__(256, 4)
void gemm_s(const u16* __restrict__ A, int lda,
            const u16* __restrict__ B, int ldb,
            void* __restrict__ Cout, int ldc,
            int N, int ksplit, size_t zElems,
            const float* __restrict__ bias)
{
    __shared__ u16 sA[64][64];
    __shared__ u16 sB[64][64];

    const int tid  = threadIdx.x;
    const int lane = tid & 63;
    const int wave = tid >> 6;

    int nxy = gridDim.x * gridDim.y;
    int id  = blockIdx.y * gridDim.x + blockIdx.x;
    int bx, by;
    if ((nxy & 7) == 0) {
        int cpx = nxy >> 3;
        int swz = (id & 7) * cpx + (id >> 3);
        bx = swz % gridDim.x;
        by = swz / gridDim.x;
    } else { bx = blockIdx.x; by = blockIdx.y; }

    const int wm = (wave >> 1) * 32;
    const int wn = (wave & 1) * 32;
    const int m0 = by * 64;
    const int n0 = bx * 64;
    const int lm = lane & 15;
    const int g  = lane >> 4;
    const int k0 = blockIdx.z * ksplit;

    const int rr = lane >> 3;
    const int sl = lane & 7;
    const int xsl = sl ^ rr;
    const u16* gA = A + (size_t)(m0 + wave * 8 + rr) * lda + k0 + xsl * 8;
    const u16* gB = B + (size_t)(n0 + wave * 8 + rr) * ldb + k0 + xsl * 8;
    const int ldsRow = (wave * 8) * 128;

    f32x4 acc[2][2] = {};

    for (int kb = 0; kb < ksplit; kb += 64) {
        #pragma unroll
        for (int c = 0; c < 2; ++c) {
            gload16(gA + (size_t)c * 32 * lda + kb, (char*)sA + c * 4096 + ldsRow);
            gload16(gB + (size_t)c * 32 * ldb + kb, (char*)sB + c * 4096 + ldsRow);
        }
        __syncthreads();

        bf16x8 af[2][2], bfr[2][2];
        #pragma unroll
        for (int h = 0; h < 2; ++h) {
            #pragma unroll
            for (int i = 0; i < 2; ++i) {
                int ra = wm + i * 16 + lm;
                int rb = wn + i * 16 + lm;
                int chunk = (((h << 2) | g) ^ (lm & 7)) << 4;
                af[h][i]  = *(const bf16x8*)((const char*)sA + ra * 128 + chunk);
                bfr[h][i] = *(const bf16x8*)((const char*)sB + rb * 128 + chunk);
            }
        }
        #pragma unroll
        for (int h = 0; h < 2; ++h)
            #pragma unroll
            for (int i = 0; i < 2; ++i)
                #pragma unroll
                for (int j = 0; j < 2; ++j)
                    acc[i][j] = __builtin_amdgcn_mfma_f32_16x16x32_bf16(af[h][i], bfr[h][j], acc[i][j], 0, 0, 0);
        __syncthreads();
    }

    #pragma unroll
    for (int i = 0; i < 2; ++i) {
        int crow = m0 + wm + i * 16 + ((lane >> 4) << 2);
        #pragma unroll
        for (int j = 0; j < 2; ++j) {
            int ccol = n0 + wn + j * 16 + lm;
            if (ccol < N) {
                #pragma unroll
                for (int r = 0; r < 4; ++r) {
                    float v = acc[i][j][r];
                    if (EPI == 1) { v += bias[ccol]; v = (v > 20.f) ? v : log1pf(__expf(v)); }
                    size_t off = (size_t)blockIdx.z * zElems + (size_t)(crow + r) * ldc + ccol;
                    if (OUTF32) ((float*)Cout)[off] = v;
                    else        ((u16*)Cout)[off]   = f2bf(v);
                }
            }
        }
    }
}

// xproj split reduce: 8 fp32 partials -> bf16. v2: 8 elems/thread (float4
// loads, uint4 store), z-order unchanged -> bitwise identical. Grid 96.
__global__ __launch_bounds__(256)
void reduce96(const float* __restrict__ splits, u16* __restrict__ xdbl)
{
    int i = blockIdx.x * 256 + threadIdx.x;   // < 24576
    float acc[8] = {};
    #pragma unroll
    for (int z = 0; z < 8; ++z) {
        const float4* p = (const float4*)(splits + (size_t)z * 196608 + (size_t)i * 8);
        float4 a = p[0], b = p[1];
        acc[0] += a.x; acc[1] += a.y; acc[2] += a.z; acc[3] += a.w;
        acc[4] += b.x; acc[5] += b.y; acc[6] += b.z; acc[7] += b.w;
    }
    union { u16 h[8]; uint4 v; } o;
    #pragma unroll
    for (int e = 0; e < 8; ++e) o.h[e] = f2bf(acc[e]);
    ((uint4*)xdbl)[i] = o.v;
}

// out_proj split reduce: 4 bf16 partials -> fp32 d_out
__global__ __launch_bounds__(256)
void reduce_out(const u16* __restrict__ parts, float* __restrict__ out)
{
    int i = blockIdx.x * 256 + threadIdx.x;
    float acc[8] = {};
    #pragma unroll
    for (int z = 0; z < 4; ++z) {
        uint4 v = ((const uint4*)(parts + (size_t)z * 2097152))[i];
        const u16* h = (const u16*)&v;
        #pragma unroll
        for (int e = 0; e < 8; ++e) acc[e] += bf2f(h[e]);
    }
    float4* o = (float4*)(out + (size_t)i * 8);
    o[0] = make_float4(acc[0], acc[1], acc[2], acc[3]);
    o[1] = make_float4(acc[4], acc[5], acc[6], acc[7]);
}

// ---------------------------------------------------------------------------
// Causal depthwise conv1d (k=4) + bias + SiLU. v2: 4 tokens x 8 ch/thread,
// 7 rows loaded once (v1 re-read 4x). FMA order per output unchanged.
// ---------------------------------------------------------------------------
__global__ __launch_bounds__(256)
void conv_silu(const u16* __restrict__ xr, const float* __restrict__ wt,
               const float* __restrict__ bias, u16* __restrict__ xs)
{
    int gi = blockIdx.x * 256 + threadIdx.x;   // 131072 threads, grid 512
    int d  = (gi & 255) * 8;
    int t0 = ((gi >> 8) & 255) * 4;
    int b  = gi >> 16;
    const u16* base = xr + (size_t)b * 4194304 + d;

    float bi[8], w8[4][8];
    {
        const float4* bp = (const float4*)(bias + d);
        float4 b0 = bp[0], b1 = bp[1];
        bi[0]=b0.x; bi[1]=b0.y; bi[2]=b0.z; bi[3]=b0.w;
        bi[4]=b1.x; bi[5]=b1.y; bi[6]=b1.z; bi[7]=b1.w;
        #pragma unroll
        for (int j = 0; j < 4; ++j) {
            const float4* wp = (const float4*)(wt + j * 2048 + d);
            float4 w0 = wp[0], w1 = wp[1];
            w8[j][0]=w0.x; w8[j][1]=w0.y; w8[j][2]=w0.z; w8[j][3]=w0.w;
            w8[j][4]=w1.x; w8[j][5]=w1.y; w8[j][6]=w1.z; w8[j][7]=w1.w;
        }
    }

    uint4 v[7];
    #pragma unroll
    for (int r = 0; r < 7; ++r) {
        int ti = t0 - 3 + r;
        v[r] = (ti >= 0) ? *(const uint4*)(base + (size_t)ti * 4096)
                         : make_uint4(0u, 0u, 0u, 0u);
    }

    #pragma unroll
    for (int tt = 0; tt < 4; ++tt) {
        float acc[8];
        #pragma unroll
        for (int e = 0; e < 8; ++e) acc[e] = bi[e];
        #pragma unroll
        for (int j = 0; j < 4; ++j) {
            const u16* h = (const u16*)&v[tt + j];
            #pragma unroll
            for (int e = 0; e < 8; ++e) acc[e] = fmaf(w8[j][e], bf2f(h[e]), acc[e]);
        }
        union { u16 h[8]; uint4 u; } o;
        #pragma unroll
        for (int e = 0; e < 8; ++e) { float x = acc[e]; o.h[e] = f2bf(x * sigm(x)); }
        *(uint4*)(xs + (size_t)b * 2097152 + (size_t)(t0 + tt) * 2048 + d) = o.u;
    }
}

// ---------------------------------------------------------------------------
// Chunked parallel scan (3-launch). Thread = one d, h[16] in registers.
// ---------------------------------------------------------------------------
template<int PHC>
__global__ __launch_bounds__(256)
void scan_chunk(const u16* __restrict__ deltag, u16* __restrict__ xsg,
                const u16* __restrict__ xdbl, const float* __restrict__ A_log,
                const u16* __restrict__ xr, float* __restrict__ summ,
                float* __restrict__ ssum)
{
    const int tid = threadIdx.x;
    const int d0 = blockIdx.x * 256;
    const int c  = blockIdx.y;
    const int b  = blockIdx.z;
    const int d  = d0 + tid;
    const int tok0 = b * 1024 + c * 32;

    __shared__ u16 s_del[32][256];
    __shared__ u16 s_uu[32][256];
    __shared__ u16 s_bc[32][32];
    __shared__ u16 s_res[PHC ? 32 : 1][PHC ? 256 : 1];
    __shared__ u16 s_y[PHC ? 32 : 1][PHC ? 256 : 1];

    for (int i = tid; i < 1024; i += 256) {
        int tl = i >> 5, v = i & 31;
        size_t tok = (size_t)(tok0 + tl);
        *(uint4*)&s_del[tl][v * 8] = *(const uint4*)&deltag[tok * 4096 + d0 + v * 8];
        *(uint4*)&s_uu[tl][v * 8]  = *(const uint4*)&xsg[tok * 2048 + d0 + v * 8];
        if (PHC)
            *(uint4*)&s_res[tl][v * 8] = *(const uint4*)&xr[tok * 4096 + 2048 + d0 + v * 8];
    }
    for (int i = tid; i < 1024; i += 256) {
        int tl = i >> 5, j = i & 31;
        s_bc[tl][j] = xdbl[(size_t)(tok0 + tl) * 96 + 64 + j];
    }

    float Ar[16], h[16];
    {
        const float4* Ap = (const float4*)(A_log + (size_t)d * 16);
        #pragma unroll
        for (int q = 0; q < 4; ++q) {
            float4 a = Ap[q];
            Ar[q * 4 + 0] = -__expf(a.x) * 1.44269504f;
            Ar[q * 4 + 1] = -__expf(a.y) * 1.44269504f;
            Ar[q * 4 + 2] = -__expf(a.z) * 1.44269504f;
            Ar[q * 4 + 3] = -__expf(a.w) * 1.44269504f;
        }
    }
    if (PHC) {
        const float4* hp = (const float4*)&summ[((size_t)(b * 32 + c) * 2048 + d) * 16];
        #pragma unroll
        for (int q = 0; q < 4; ++q) {
            float4 v = hp[q];
            h[q * 4 + 0] = v.x; h[q * 4 + 1] = v.y; h[q * 4 + 2] = v.z; h[q * 4 + 3] = v.w;
        }
    } else {
        #pragma unroll
        for (int n = 0; n < 16; ++n) h[n] = 0.f;
    }
    __syncthreads();

    float S = 0.f;
    #pragma unroll 4
    for (int tl = 0; tl < 32; ++tl) {
        float dlt = bf2f(s_del[tl][tid]);
        float du = dlt * bf2f(s_uu[tl][tid]);
        if (!PHC) S += dlt;
        #pragma unroll
        for (int n = 0; n < 16; ++n)
            h[n] = fmaf(ex2(dlt * Ar[n]), h[n], du * bf2f(s_bc[tl][n]));
        if (PHC) {
            float y = 0.f;
            #pragma unroll
            for (int n = 0; n < 16; ++n)
                y = fmaf(h[n], bf2f(s_bc[tl][16 + n]), y);
            s_y[tl][tid] = f2bf(y * bf2f(s_res[tl][tid]));
        }
    }

    if (!PHC) {
        float4* bp = (float4*)&summ[((size_t)(b * 32 + c) * 2048 + d) * 16];
        #pragma unroll
        for (int q = 0; q < 4; ++q)
            bp[q] = make_float4(h[q * 4], h[q * 4 + 1], h[q * 4 + 2], h[q * 4 + 3]);
        ssum[(size_t)(b * 32 + c) * 2048 + d] = S;
    } else {
        __syncthreads();
        for (int i = tid; i < 1024; i += 256) {
            int tl = i >> 5, v = i & 31;
            *(uint4*)&xsg[(size_t)(tok0 + tl) * 2048 + d0 + v * 8] = *(uint4*)&s_y[tl][v * 8];
        }
    }
}

// phaseB: prefix-combine across 32 chunks, loads preloaded into VGPRs.
__global__ __launch_bounds__(256)
void scan_phaseB(float* __restrict__ summ, const float* __restrict__ ssum,
                 const float* __restrict__ A_log)
{
    int g = blockIdx.x * 256 + threadIdx.x;
    int n = g & 15;
    int d = (g >> 4) & 2047;
    int b = g >> 15;
    float An2 = -__expf(A_log[(size_t)d * 16 + n]) * 1.44269504f;
    size_t base = ((size_t)(b * 32) * 2048 + d) * 16 + n;
    float bc[32], Sc[32];
    #pragma unroll
    for (int c = 0; c < 32; ++c) bc[c] = summ[base + (size_t)c * 32768];
    #pragma unroll
    for (int c = 0; c < 32; ++c) Sc[c] = ssum[(size_t)(b * 32 + c) * 2048 + d];
    float h = 0.f;
    #pragma unroll
    for (int c = 0; c < 32; ++c) {
        float nb = bc[c];
        bc[c] = h;
        h = fmaf(ex2(An2 * Sc[c]), h, nb);
    }
    #pragma unroll
    for (int c = 0; c < 32; ++c) summ[base + (size_t)c * 32768] = bc[c];
}

__global__ void sentinel_kernel(float* out, float v) { out[0] = v; }

// ---------------------------------------------------------------------------
extern "C" void kernel_launch(void* const* d_in, const int* in_sizes, int n_in,
                              void* d_out, int out_size, void* d_ws, size_t ws_size,
                              hipStream_t stream)
{
    const float* x         = (const float*)d_in[0];
    const float* in_w      = (const float*)d_in[1];
    const float* conv_w    = (const float*)d_in[2];
    const float* conv_b    = (const float*)d_in[3];
    const float* xproj_w   = (const float*)d_in[4];
    const float* dtproj_w  = (const float*)d_in[5];
    const float* dtproj_b  = (const float*)d_in[6];
    const float* A_log     = (const float*)d_in[7];
    const float* outproj_w = (const float*)d_in[8];
    float* out = (float*)d_out;

    static const int EXP[9] = {2097152, 4194304, 8192, 2048, 196608, 131072, 2048, 32768, 2097152};
    int bad = -1;
    if (n_in != 9) bad = 9;
    else { for (int i = 0; i < 9; ++i) if (in_sizes[i] != EXP[i]) { bad = i; break; } }
    if (bad < 0 && out_size != 2097152) bad = 10;
    if (bad < 0 && ws_size < 34734080u) bad = 11;
    if (bad >= 0) {
        sentinel_kernel<<<1, 1, 0, stream>>>(out, 131072.f * (1.f + (float)bad / 16.f));
        return;
    }

    // ws: xr 16.78M | xs 8.39M | xdbl 0.39M | region R 9.18M (phased)
    char* ws = (char*)d_ws;
    u16*   xr      = (u16*)(ws);              // [2048][4096]; dead after scan -> out partials
    u16*   xs      = (u16*)(ws + 16777216);   // [2048][2048] x_bf -> u -> yg
    u16*   xdbl    = (u16*)(ws + 25165824);   // [2048][96]
    char*  R       = ws + 25559040;
    u16*   x_bf    = xs;                      // borrow xs pre-conv
    u16*   inw_bf  = (u16*)(R);               // 8.39M (phase 1)
    u16*   xpw_bf  = (u16*)(R + 8388608);     // 0.52M (phase 1-2)
    float* wt      = (float*)(R + 8912896);   // 32K transposed conv w (phase 1-2)
    u16*   dtw_bf  = (u16*)out;               // 0.26M in dead d_out (live until step 4)
    u16*   opw_bf  = (u16*)((char*)out + 262144); // 4.19M in dead d_out (live until step 6;
                                              // reduce_out overwrites d_out at the very end)
    float* splits  = (float*)(R);             // 6.29M (phase 2, inw dead)
    float* summ    = (float*)(R);             // 8.39M (phase 3, splits dead)
    float* ssum    = (float*)(R + 8388608);   // 0.52M (phase 3, xpw/wt dead)
    u16*   oparts  = xr;                      // 16.78M = 4 x [2048][1024] bf16 (xr dead)

    // 0) merged front conversions (x, in_w, xproj pad, dtw, out_proj w, conv-w)
    cvt_front<<<4320, 256, 0, stream>>>(x, in_w, xproj_w, conv_w, dtproj_w, outproj_w,
                                        x_bf, inw_bf, xpw_bf, wt, dtw_bf, opw_bf);
    // 1) in_proj (+silu on res half): 2048x4096, K=1024.
    //    64x128 tile, 2-phase dbuf -> grid (32,32) = 1024 blocks, 3 blk/CU.
    gemm_w<2, false><<<dim3(32, 32, 1), 256, 0, stream>>>(
        x_bf, 1024, inw_bf, 1024, xr, 4096, 4096, 1024, 0, nullptr);
    // 2) conv + silu -> xs (overwrites x_bf); v2 row-reuse, grid 512
    conv_silu<<<512, 256, 0, stream>>>(xr, wt, conv_b, xs);
    // 3) x_proj split-K=8, 64-tile
    gemm_s<0, true><<<dim3(2, 32, 8), 256, 0, stream>>>(
        xs, 2048, xpw_bf, 2048, splits, 96, 96, 256, 196608, nullptr);
    reduce96<<<96, 256, 0, stream>>>(splits, xdbl);
    // 4) delta = softplus(xdbl[:,:64] @ dtw^T + b), 64-tile MFMA
    gemm_s<1, false><<<dim3(32, 32, 1), 256, 0, stream>>>(
        xdbl, 96, dtw_bf, 64, xr, 4096, 2048, 64, 0, dtproj_b);
    // 5) chunked scan A -> B -> C (yg in-place over xs)
    scan_chunk<0><<<dim3(8, 32, 2), 256, 0, stream>>>(xr, xs, xdbl, A_log, xr, summ, ssum);
    scan_phaseB<<<256, 256, 0, stream>>>(summ, ssum, A_log);
    scan_chunk<1><<<dim3(8, 32, 2), 256, 0, stream>>>(xr, xs, xdbl, A_log, xr, summ, ssum);
    // 6) out_proj split-K=4, 128x128 tile (weights pre-converted in cvt_front)
    gemm2<0, false><<<dim3(8, 16, 4), 256, 0, stream>>>(
        xs, 2048, opw_bf, 2048, oparts, 1024, 1024, 512, 2097152, nullptr);
    reduce_out<<<1024, 256, 0, stream>>>(oparts, out);
}

// Round 13
// 218.596 us; speedup vs baseline: 1.0414x; 1.0414x over previous
//
#include <hip/hip_runtime.h>

typedef unsigned short u16;
typedef __bf16 bf16x8 __attribute__((ext_vector_type(8)));
typedef float f32x4 __attribute__((ext_vector_type(4)));

__device__ inline float bf2f(u16 u) {
    unsigned int x = ((unsigned int)u) << 16;
    return __builtin_bit_cast(float, x);
}
__device__ inline u16 f2bf(float f) {
    unsigned int x = __builtin_bit_cast(unsigned int, f);
    return (u16)((x + 0x7FFFu + ((x >> 16) & 1u)) >> 16);
}
__device__ inline float sigm(float v) { return 1.f / (1.f + __expf(-v)); }
// 2^x via v_exp_f32 (ISA: D = 2^S0). Callers pre-fold log2e into the operand.
__device__ inline float ex2(float x) {
    float r; asm("v_exp_f32 %0, %1" : "=v"(r) : "v"(x)); return r;
}

__device__ __forceinline__ void gload16(const void* g, void* l) {
    __builtin_amdgcn_global_load_lds(
        (const __attribute__((address_space(1))) void*)g,
        (__attribute__((address_space(3))) void*)l, 16, 0, 0);
}

__device__ inline uint4 pack8(const float* p) {
    const float4* q = (const float4*)p;
    float4 a = q[0], b = q[1];
    union { u16 h[8]; uint4 v; } u;
    u.h[0] = f2bf(a.x); u.h[1] = f2bf(a.y); u.h[2] = f2bf(a.z); u.h[3] = f2bf(a.w);
    u.h[4] = f2bf(b.x); u.h[5] = f2bf(b.y); u.h[6] = f2bf(b.z); u.h[7] = f2bf(b.w);
    return u.v;
}

// ---------------------------------------------------------------------------
// Merged front conversions: x (1024 blk) | in_w (2048) | xproj pad (128) |
// dtw (64) | out_proj w (1024, parked in d_out) | conv_w transpose (32).
// ---------------------------------------------------------------------------
__global__ __launch_bounds__(256)
void cvt_front(const float* __restrict__ x, const float* __restrict__ inw,
               const float* __restrict__ xpw, const float* __restrict__ convw,
               const float* __restrict__ dtw, const float* __restrict__ opw,
               u16* __restrict__ x_bf, u16* __restrict__ inw_bf,
               u16* __restrict__ xpw_bf, float* __restrict__ wt,
               u16* __restrict__ dtw_bf, u16* __restrict__ opw_bf)
{
    int bk = blockIdx.x, tid = threadIdx.x;
    if (bk < 1024) {
        int i = bk * 256 + tid;
        ((uint4*)x_bf)[i] = pack8(x + (size_t)i * 8);
    } else if (bk < 3072) {
        int i = (bk - 1024) * 256 + tid;
        ((uint4*)inw_bf)[i] = pack8(inw + (size_t)i * 8);
    } else if (bk < 3200) {
        int i = (bk - 3072) * 256 + tid;
        int row = (i * 8) >> 11;
        ((uint4*)xpw_bf)[i] = (row < 96) ? pack8(xpw + (size_t)row * 2048 + ((i * 8) & 2047))
                                         : make_uint4(0u, 0u, 0u, 0u);
    } else if (bk < 3264) {
        int i = (bk - 3200) * 256 + tid;   // < 16384 (131072 elems / 8)
        ((uint4*)dtw_bf)[i] = pack8(dtw + (size_t)i * 8);
    } else if (bk < 4288) {
        int i = (bk - 3264) * 256 + tid;   // < 262144 (2M elems / 8)
        ((uint4*)opw_bf)[i] = pack8(opw + (size_t)i * 8);
    } else {
        int i = (bk - 4288) * 256 + tid;   // < 8192
        wt[(i & 3) * 2048 + (i >> 2)] = convw[i];
    }
}

// ---------------------------------------------------------------------------
// MFMA NT GEMM, 128x128 tile, BK=64, gload_lds w16 + XOR-swizzle, XCD swizzle.
// For out_proj (r10: BM=64 doubles B-panel re-reads, ~+10us there).
// EPI: 0 none; 1 softplus(acc+bias[col]); 2 silu on cols>=2048.
// ---------------------------------------------------------------------------
template<int EPI, bool OUTF32>
__global__ __launch_bounds__(256, 4)
void gemm2(const u16* __restrict__ A, int lda,
           const u16* __restrict__ B, int ldb,
           void* __restrict__ Cout, int ldc,
           int N, int ksplit, size_t zElems,
           const float* __restrict__ bias)
{
    __shared__ u16 sA[128][64];
    __shared__ u16 sB[128][64];

    const int tid  = threadIdx.x;
    const int lane = tid & 63;
    const int wave = tid >> 6;

    int nxy = gridDim.x * gridDim.y;
    int id  = blockIdx.y * gridDim.x + blockIdx.x;
    int bx, by;
    if ((nxy & 7) == 0) {
        int cpx = nxy >> 3;
        int swz = (id & 7) * cpx + (id >> 3);
        bx = swz % gridDim.x;
        by = swz / gridDim.x;
    } else { bx = blockIdx.x; by = blockIdx.y; }

    const int wm = (wave >> 1) * 64;
    const int wn = (wave & 1) * 64;
    const int m0 = by * 128;
    const int n0 = bx * 128;
    const int lm = lane & 15;
    const int g  = lane >> 4;
    const int k0 = blockIdx.z * ksplit;

    const int rr = lane >> 3;
    const int sl = lane & 7;
    const int xsl = sl ^ rr;
    const u16* gA = A + (size_t)(m0 + wave * 8 + rr) * lda + k0 + xsl * 8;
    const u16* gB = B + (size_t)(n0 + wave * 8 + rr) * ldb + k0 + xsl * 8;
    const int ldsRow = (wave * 8) * 128;

    f32x4 acc[4][4] = {};

    for (int kb = 0; kb < ksplit; kb += 64) {
        #pragma unroll
        for (int c = 0; c < 4; ++c) {
            gload16(gA + (size_t)c * 32 * lda + kb, (char*)sA + c * 4096 + ldsRow);
            gload16(gB + (size_t)c * 32 * ldb + kb, (char*)sB + c * 4096 + ldsRow);
        }
        __syncthreads();

        bf16x8 af[2][4], bfr[2][4];
        #pragma unroll
        for (int h = 0; h < 2; ++h) {
            #pragma unroll
            for (int i = 0; i < 4; ++i) {
                int ra = wm + i * 16 + lm;
                int rb = wn + i * 16 + lm;
                int chunk = (((h << 2) | g) ^ (lm & 7)) << 4;
                af[h][i]  = *(const bf16x8*)((const char*)sA + ra * 128 + chunk);
                bfr[h][i] = *(const bf16x8*)((const char*)sB + rb * 128 + chunk);
            }
        }
        #pragma unroll
        for (int h = 0; h < 2; ++h)
            #pragma unroll
            for (int i = 0; i < 4; ++i)
                #pragma unroll
                for (int j = 0; j < 4; ++j)
                    acc[i][j] = __builtin_amdgcn_mfma_f32_16x16x32_bf16(af[h][i], bfr[h][j], acc[i][j], 0, 0, 0);
        __syncthreads();
    }

    #pragma unroll
    for (int i = 0; i < 4; ++i) {
        int crow = m0 + wm + i * 16 + ((lane >> 4) << 2);
        #pragma unroll
        for (int j = 0; j < 4; ++j) {
            int ccol = n0 + wn + j * 16 + lm;
            if (ccol < N) {
                #pragma unroll
                for (int r = 0; r < 4; ++r) {
                    float v = acc[i][j][r];
                    if (EPI == 1) { v += bias[ccol]; v = (v > 20.f) ? v : log1pf(__expf(v)); }
                    if (EPI == 2 && ccol >= 2048) v *= sigm(v);
                    size_t off = (size_t)blockIdx.z * zElems + (size_t)(crow + r) * ldc + ccol;
                    if (OUTF32) ((float*)Cout)[off] = v;
                    else        ((u16*)Cout)[off]   = f2bf(v);
                }
            }
        }
    }
}

// ---------------------------------------------------------------------------
// MFMA NT GEMM, 64x128 tile, BK=64, 24 KB LDS, 4 blocks/CU. SINGLE-buffered
// (r12 tried 2-phase dbuf: 49.6us vs ~40 — LDS 2x cut occupancy 4->3 and the
// __syncthreads still drains vmcnt(0); reverted per m99/m131-m140).
// For in_proj.
// ---------------------------------------------------------------------------
template<int EPI, bool OUTF32>
__global__ __launch_bounds__(256, 4)
void gemm_w(const u16* __restrict__ A, int lda,
            const u16* __restrict__ B, int ldb,
            void* __restrict__ Cout, int ldc,
            int N, int ksplit, size_t zElems,
            const float* __restrict__ bias)
{
    __shared__ u16 sA[64][64];    // 8 KB
    __shared__ u16 sB[128][64];   // 16 KB

    const int tid  = threadIdx.x;
    const int lane = tid & 63;
    const int wave = tid >> 6;

    int nxy = gridDim.x * gridDim.y;
    int id  = blockIdx.y * gridDim.x + blockIdx.x;
    int bx, by;
    if ((nxy & 7) == 0) {
        int cpx = nxy >> 3;
        int swz = (id & 7) * cpx + (id >> 3);
        bx = swz % gridDim.x;
        by = swz / gridDim.x;
    } else { bx = blockIdx.x; by = blockIdx.y; }

    const int wm = (wave >> 1) * 32;     // rows: 2 wave-rows of 32
    const int wn = (wave & 1) * 64;      // cols: 2 wave-cols of 64
    const int m0 = by * 64;
    const int n0 = bx * 128;
    const int lm = lane & 15;
    const int g  = lane >> 4;
    const int k0 = blockIdx.z * ksplit;

    const int rr = lane >> 3;
    const int sl = lane & 7;
    const int xsl = sl ^ rr;
    const u16* gA = A + (size_t)(m0 + wave * 8 + rr) * lda + k0 + xsl * 8;
    const u16* gB = B + (size_t)(n0 + wave * 8 + rr) * ldb + k0 + xsl * 8;
    const int ldsRow = (wave * 8) * 128;

    f32x4 acc[2][4] = {};

    for (int kb = 0; kb < ksplit; kb += 64) {
        #pragma unroll
        for (int c = 0; c < 2; ++c)
            gload16(gA + (size_t)c * 32 * lda + kb, (char*)sA + c * 4096 + ldsRow);
        #pragma unroll
        for (int c = 0; c < 4; ++c)
            gload16(gB + (size_t)c * 32 * ldb + kb, (char*)sB + c * 4096 + ldsRow);
        __syncthreads();

        bf16x8 af[2][2], bfr[2][4];
        #pragma unroll
        for (int h = 0; h < 2; ++h) {
            int chunk = (((h << 2) | g) ^ (lm & 7)) << 4;
            #pragma unroll
            for (int i = 0; i < 2; ++i)
                af[h][i]  = *(const bf16x8*)((const char*)sA + (wm + i * 16 + lm) * 128 + chunk);
            #pragma unroll
            for (int j = 0; j < 4; ++j)
                bfr[h][j] = *(const bf16x8*)((const char*)sB + (wn + j * 16 + lm) * 128 + chunk);
        }
        #pragma unroll
        for (int h = 0; h < 2; ++h)
            #pragma unroll
            for (int i = 0; i < 2; ++i)
                #pragma unroll
                for (int j = 0; j < 4; ++j)
                    acc[i][j] = __builtin_amdgcn_mfma_f32_16x16x32_bf16(af[h][i], bfr[h][j], acc[i][j], 0, 0, 0);
        __syncthreads();
    }

    #pragma unroll
    for (int i = 0; i < 2; ++i) {
        int crow = m0 + wm + i * 16 + ((lane >> 4) << 2);
        #pragma unroll
        for (int j = 0; j < 4; ++j) {
            int ccol = n0 + wn + j * 16 + lm;
            if (ccol < N) {
                #pragma unroll
                for (int r = 0; r < 4; ++r) {
                    float v = acc[i][j][r];
                    if (EPI == 1) { v += bias[ccol]; v = (v > 20.f) ? v : log1pf(__expf(v)); }
                    if (EPI == 2 && ccol >= 2048) v *= sigm(v);
                    size_t off = (size_t)blockIdx.z * zElems + (size_t)(crow + r) * ldc + ccol;
                    if (OUTF32) ((float*)Cout)[off] = v;
                    else        ((u16*)Cout)[off]   = f2bf(v);
                }
            }
        }
    }
}

// ---------------------------------------------------------------------------
// MFMA NT GEMM, 64x64 tile, 16 KB LDS, 4 blocks/CU (16 waves/CU).
// For small/latency-bound shapes (dt K=64, x_proj).
// ---------------------------------------------------------------------------
template<int EPI, bool OUTF32>
__global__ __launch_bounds__(256, 4)
void gemm_s(const u16* __restrict__ A, int lda,
            const u16* __restrict__ B, int ldb,
            void* __restrict__ Cout, int ldc,
            int N, int ksplit, size_t zElems,
            const float* __restrict__ bias)
{
    __shared__ u16 sA[64][64];
    __shared__ u16 sB[64][64];

    const int tid  = threadIdx.x;
    const int lane = tid & 63;
    const int wave = tid >> 6;

    int nxy = gridDim.x * gridDim.y;
    int id  = blockIdx.y * gridDim.x + blockIdx.x;
    int bx, by;
    if ((nxy & 7) == 0) {
        int cpx = nxy >> 3;
        int swz = (id & 7) * cpx + (id >> 3);
        bx = swz % gridDim.x;
        by = swz / gridDim.x;
    } else { bx = blockIdx.x; by = blockIdx.y; }

    const int wm = (wave >> 1) * 32;
    const int wn = (wave & 1) * 32;
    const int m0 = by * 64;
    const int n0 = bx * 64;
    const int lm = lane & 15;
    const int g  = lane >> 4;
    const int k0 = blockIdx.z * ksplit;

    const int rr = lane >> 3;
    const int sl = lane & 7;
    const int xsl = sl ^ rr;
    const u16* gA = A + (size_t)(m0 + wave * 8 + rr) * lda + k0 + xsl * 8;
    const u16* gB = B + (size_t)(n0 + wave * 8 + rr) * ldb + k0 + xsl * 8;
    const int ldsRow = (wave * 8) * 128;

    f32x4 acc[2][2] = {};

    for (int kb = 0; kb < ksplit; kb += 64) {
        #pragma unroll
        for (int c = 0; c < 2; ++c) {
            gload16(gA + (size_t)c * 32 * lda + kb, (char*)sA + c * 4096 + ldsRow);
            gload16(gB + (size_t)c * 32 * ldb + kb, (char*)sB + c * 4096 + ldsRow);
        }
        __syncthreads();

        bf16x8 af[2][2], bfr[2][2];
        #pragma unroll
        for (int h = 0; h < 2; ++h) {
            #pragma unroll
            for (int i = 0; i < 2; ++i) {
                int ra = wm + i * 16 + lm;
                int rb = wn + i * 16 + lm;
                int chunk = (((h << 2) | g) ^ (lm & 7)) << 4;
                af[h][i]  = *(const bf16x8*)((const char*)sA + ra * 128 + chunk);
                bfr[h][i] = *(const bf16x8*)((const char*)sB + rb * 128 + chunk);
            }
        }
        #pragma unroll
        for (int h = 0; h < 2; ++h)
            #pragma unroll
            for (int i = 0; i < 2; ++i)
                #pragma unroll
                for (int j = 0; j < 2; ++j)
                    acc[i][j] = __builtin_amdgcn_mfma_f32_16x16x32_bf16(af[h][i], bfr[h][j], acc[i][j], 0, 0, 0);
        __syncthreads();
    }

    #pragma unroll
    for (int i = 0; i < 2; ++i) {
        int crow = m0 + wm + i * 16 + ((lane >> 4) << 2);
        #pragma unroll
        for (int j = 0; j < 2; ++j) {
            int ccol = n0 + wn + j * 16 + lm;
            if (ccol < N) {
                #pragma unroll
                for (int r = 0; r < 4; ++r) {
                    float v = acc[i][j][r];
                    if (EPI == 1) { v += bias[ccol]; v = (v > 20.f) ? v : log1pf(__expf(v)); }
                    size_t off = (size_t)blockIdx.z * zElems + (size_t)(crow + r) * ldc + ccol;
                    if (OUTF32) ((float*)Cout)[off] = v;
                    else        ((u16*)Cout)[off]   = f2bf(v);
                }
            }
        }
    }
}

// xproj split reduce: 8 fp32 partials -> bf16. v2: 8 elems/thread (float4
// loads, uint4 store), z-order unchanged -> bitwise identical. Grid 96.
__global__ __launch_bounds__(256)
void reduce96(const float* __restrict__ splits, u16* __restrict__ xdbl)
{
    int i = blockIdx.x * 256 + threadIdx.x;   // < 24576
    float acc[8] = {};
    #pragma unroll
    for (int z = 0; z < 8; ++z) {
        const float4* p = (const float4*)(splits + (size_t)z * 196608 + (size_t)i * 8);
        float4 a = p[0], b = p[1];
        acc[0] += a.x; acc[1] += a.y; acc[2] += a.z; acc[3] += a.w;
        acc[4] += b.x; acc[5] += b.y; acc[6] += b.z; acc[7] += b.w;
    }
    union { u16 h[8]; uint4 v; } o;
    #pragma unroll
    for (int e = 0; e < 8; ++e) o.h[e] = f2bf(acc[e]);
    ((uint4*)xdbl)[i] = o.v;
}

// out_proj split reduce: 4 bf16 partials -> fp32 d_out
__global__ __launch_bounds__(256)
void reduce_out(const u16* __restrict__ parts, float* __restrict__ out)
{
    int i = blockIdx.x * 256 + threadIdx.x;
    float acc[8] = {};
    #pragma unroll
    for (int z = 0; z < 4; ++z) {
        uint4 v = ((const uint4*)(parts + (size_t)z * 2097152))[i];
        const u16* h = (const u16*)&v;
        #pragma unroll
        for (int e = 0; e < 8; ++e) acc[e] += bf2f(h[e]);
    }
    float4* o = (float4*)(out + (size_t)i * 8);
    o[0] = make_float4(acc[0], acc[1], acc[2], acc[3]);
    o[1] = make_float4(acc[4], acc[5], acc[6], acc[7]);
}

// ---------------------------------------------------------------------------
// Causal depthwise conv1d (k=4) + bias + SiLU. v2: 4 tokens x 8 ch/thread,
// 7 rows loaded once (v1 re-read 4x). FMA order per output unchanged.
// ---------------------------------------------------------------------------
__global__ __launch_bounds__(256)
void conv_silu(const u16* __restrict__ xr, const float* __restrict__ wt,
               const float* __restrict__ bias, u16* __restrict__ xs)
{
    int gi = blockIdx.x * 256 + threadIdx.x;   // 131072 threads, grid 512
    int d  = (gi & 255) * 8;
    int t0 = ((gi >> 8) & 255) * 4;
    int b  = gi >> 16;
    const u16* base = xr + (size_t)b * 4194304 + d;

    float bi[8], w8[4][8];
    {
        const float4* bp = (const float4*)(bias + d);
        float4 b0 = bp[0], b1 = bp[1];
        bi[0]=b0.x; bi[1]=b0.y; bi[2]=b0.z; bi[3]=b0.w;
        bi[4]=b1.x; bi[5]=b1.y; bi[6]=b1.z; bi[7]=b1.w;
        #pragma unroll
        for (int j = 0; j < 4; ++j) {
            const float4* wp = (const float4*)(wt + j * 2048 + d);
            float4 w0 = wp[0], w1 = wp[1];
            w8[j][0]=w0.x; w8[j][1]=w0.y; w8[j][2]=w0.z; w8[j][3]=w0.w;
            w8[j][4]=w1.x; w8[j][5]=w1.y; w8[j][6]=w1.z; w8[j][7]=w1.w;
        }
    }

    uint4 v[7];
    #pragma unroll
    for (int r = 0; r < 7; ++r) {
        int ti = t0 - 3 + r;
        v[r] = (ti >= 0) ? *(const uint4*)(base + (size_t)ti * 4096)
                         : make_uint4(0u, 0u, 0u, 0u);
    }

    #pragma unroll
    for (int tt = 0; tt < 4; ++tt) {
        float acc[8];
        #pragma unroll
        for (int e = 0; e < 8; ++e) acc[e] = bi[e];
        #pragma unroll
        for (int j = 0; j < 4; ++j) {
            const u16* h = (const u16*)&v[tt + j];
            #pragma unroll
            for (int e = 0; e < 8; ++e) acc[e] = fmaf(w8[j][e], bf2f(h[e]), acc[e]);
        }
        union { u16 h[8]; uint4 u; } o;
        #pragma unroll
        for (int e = 0; e < 8; ++e) { float x = acc[e]; o.h[e] = f2bf(x * sigm(x)); }
        *(uint4*)(xs + (size_t)b * 2097152 + (size_t)(t0 + tt) * 2048 + d) = o.u;
    }
}

// ---------------------------------------------------------------------------
// Chunked parallel scan (3-launch). Thread = one d, h[16] in registers.
// ---------------------------------------------------------------------------
template<int PHC>
__global__ __launch_bounds__(256)
void scan_chunk(const u16* __restrict__ deltag, u16* __restrict__ xsg,
                const u16* __restrict__ xdbl, const float* __restrict__ A_log,
                const u16* __restrict__ xr, float* __restrict__ summ,
                float* __restrict__ ssum)
{
    const int tid = threadIdx.x;
    const int d0 = blockIdx.x * 256;
    const int c  = blockIdx.y;
    const int b  = blockIdx.z;
    const int d  = d0 + tid;
    const int tok0 = b * 1024 + c * 32;

    __shared__ u16 s_del[32][256];
    __shared__ u16 s_uu[32][256];
    __shared__ u16 s_bc[32][32];
    __shared__ u16 s_res[PHC ? 32 : 1][PHC ? 256 : 1];
    __shared__ u16 s_y[PHC ? 32 : 1][PHC ? 256 : 1];

    for (int i = tid; i < 1024; i += 256) {
        int tl = i >> 5, v = i & 31;
        size_t tok = (size_t)(tok0 + tl);
        *(uint4*)&s_del[tl][v * 8] = *(const uint4*)&deltag[tok * 4096 + d0 + v * 8];
        *(uint4*)&s_uu[tl][v * 8]  = *(const uint4*)&xsg[tok * 2048 + d0 + v * 8];
        if (PHC)
            *(uint4*)&s_res[tl][v * 8] = *(const uint4*)&xr[tok * 4096 + 2048 + d0 + v * 8];
    }
    for (int i = tid; i < 1024; i += 256) {
        int tl = i >> 5, j = i & 31;
        s_bc[tl][j] = xdbl[(size_t)(tok0 + tl) * 96 + 64 + j];
    }

    float Ar[16], h[16];
    {
        const float4* Ap = (const float4*)(A_log + (size_t)d * 16);
        #pragma unroll
        for (int q = 0; q < 4; ++q) {
            float4 a = Ap[q];
            Ar[q * 4 + 0] = -__expf(a.x) * 1.44269504f;
            Ar[q * 4 + 1] = -__expf(a.y) * 1.44269504f;
            Ar[q * 4 + 2] = -__expf(a.z) * 1.44269504f;
            Ar[q * 4 + 3] = -__expf(a.w) * 1.44269504f;
        }
    }
    if (PHC) {
        const float4* hp = (const float4*)&summ[((size_t)(b * 32 + c) * 2048 + d) * 16];
        #pragma unroll
        for (int q = 0; q < 4; ++q) {
            float4 v = hp[q];
            h[q * 4 + 0] = v.x; h[q * 4 + 1] = v.y; h[q * 4 + 2] = v.z; h[q * 4 + 3] = v.w;
        }
    } else {
        #pragma unroll
        for (int n = 0; n < 16; ++n) h[n] = 0.f;
    }
    __syncthreads();

    float S = 0.f;
    #pragma unroll 4
    for (int tl = 0; tl < 32; ++tl) {
        float dlt = bf2f(s_del[tl][tid]);
        float du = dlt * bf2f(s_uu[tl][tid]);
        if (!PHC) S += dlt;
        #pragma unroll
        for (int n = 0; n < 16; ++n)
            h[n] = fmaf(ex2(dlt * Ar[n]), h[n], du * bf2f(s_bc[tl][n]));
        if (PHC) {
            float y = 0.f;
            #pragma unroll
            for (int n = 0; n < 16; ++n)
                y = fmaf(h[n], bf2f(s_bc[tl][16 + n]), y);
            s_y[tl][tid] = f2bf(y * bf2f(s_res[tl][tid]));
        }
    }

    if (!PHC) {
        float4* bp = (float4*)&summ[((size_t)(b * 32 + c) * 2048 + d) * 16];
        #pragma unroll
        for (int q = 0; q < 4; ++q)
            bp[q] = make_float4(h[q * 4], h[q * 4 + 1], h[q * 4 + 2], h[q * 4 + 3]);
        ssum[(size_t)(b * 32 + c) * 2048 + d] = S;
    } else {
        __syncthreads();
        for (int i = tid; i < 1024; i += 256) {
            int tl = i >> 5, v = i & 31;
            *(uint4*)&xsg[(size_t)(tok0 + tl) * 2048 + d0 + v * 8] = *(uint4*)&s_y[tl][v * 8];
        }
    }
}

// phaseB: prefix-combine across 32 chunks, loads preloaded into VGPRs.
__global__ __launch_bounds__(256)
void scan_phaseB(float* __restrict__ summ, const float* __restrict__ ssum,
                 const float* __restrict__ A_log)
{
    int g = blockIdx.x * 256 + threadIdx.x;
    int n = g & 15;
    int d = (g >> 4) & 2047;
    int b = g >> 15;
    float An2 = -__expf(A_log[(size_t)d * 16 + n]) * 1.44269504f;
    size_t base = ((size_t)(b * 32) * 2048 + d) * 16 + n;
    float bc[32], Sc[32];
    #pragma unroll
    for (int c = 0; c < 32; ++c) bc[c] = summ[base + (size_t)c * 32768];
    #pragma unroll
    for (int c = 0; c < 32; ++c) Sc[c] = ssum[(size_t)(b * 32 + c) * 2048 + d];
    float h = 0.f;
    #pragma unroll
    for (int c = 0; c < 32; ++c) {
        float nb = bc[c];
        bc[c] = h;
        h = fmaf(ex2(An2 * Sc[c]), h, nb);
    }
    #pragma unroll
    for (int c = 0; c < 32; ++c) summ[base + (size_t)c * 32768] = bc[c];
}

__global__ void sentinel_kernel(float* out, float v) { out[0] = v; }

// ---------------------------------------------------------------------------
extern "C" void kernel_launch(void* const* d_in, const int* in_sizes, int n_in,
                              void* d_out, int out_size, void* d_ws, size_t ws_size,
                              hipStream_t stream)
{
    const float* x         = (const float*)d_in[0];
    const float* in_w      = (const float*)d_in[1];
    const float* conv_w    = (const float*)d_in[2];
    const float* conv_b    = (const float*)d_in[3];
    const float* xproj_w   = (const float*)d_in[4];
    const float* dtproj_w  = (const float*)d_in[5];
    const float* dtproj_b  = (const float*)d_in[6];
    const float* A_log     = (const float*)d_in[7];
    const float* outproj_w = (const float*)d_in[8];
    float* out = (float*)d_out;

    static const int EXP[9] = {2097152, 4194304, 8192, 2048, 196608, 131072, 2048, 32768, 2097152};
    int bad = -1;
    if (n_in != 9) bad = 9;
    else { for (int i = 0; i < 9; ++i) if (in_sizes[i] != EXP[i]) { bad = i; break; } }
    if (bad < 0 && out_size != 2097152) bad = 10;
    if (bad < 0 && ws_size < 34734080u) bad = 11;
    if (bad >= 0) {
        sentinel_kernel<<<1, 1, 0, stream>>>(out, 131072.f * (1.f + (float)bad / 16.f));
        return;
    }

    // ws: xr 16.78M | xs 8.39M | xdbl 0.39M | region R 9.18M (phased)
    char* ws = (char*)d_ws;
    u16*   xr      = (u16*)(ws);              // [2048][4096]; dead after scan -> out partials
    u16*   xs      = (u16*)(ws + 16777216);   // [2048][2048] x_bf -> u -> yg
    u16*   xdbl    = (u16*)(ws + 25165824);   // [2048][96]
    char*  R       = ws + 25559040;
    u16*   x_bf    = xs;                      // borrow xs pre-conv
    u16*   inw_bf  = (u16*)(R);               // 8.39M (phase 1)
    u16*   xpw_bf  = (u16*)(R + 8388608);     // 0.52M (phase 1-2)
    float* wt      = (float*)(R + 8912896);   // 32K transposed conv w (phase 1-2)
    u16*   dtw_bf  = (u16*)out;               // 0.26M in dead d_out (live until step 4)
    u16*   opw_bf  = (u16*)((char*)out + 262144); // 4.19M in dead d_out (live until step 6;
                                              // reduce_out overwrites d_out at the very end)
    float* splits  = (float*)(R);             // 6.29M (phase 2, inw dead)
    float* summ    = (float*)(R);             // 8.39M (phase 3, splits dead)
    float* ssum    = (float*)(R + 8388608);   // 0.52M (phase 3, xpw/wt dead)
    u16*   oparts  = xr;                      // 16.78M = 4 x [2048][1024] bf16 (xr dead)

    // 0) merged front conversions (x, in_w, xproj pad, dtw, out_proj w, conv-w)
    cvt_front<<<4320, 256, 0, stream>>>(x, in_w, xproj_w, conv_w, dtproj_w, outproj_w,
                                        x_bf, inw_bf, xpw_bf, wt, dtw_bf, opw_bf);
    // 1) in_proj (+silu on res half): 2048x4096, K=1024.
    //    64x128 tile, single-buffered -> grid (32,32) = 1024 blocks, 4 blk/CU.
    gemm_w<2, false><<<dim3(32, 32, 1), 256, 0, stream>>>(
        x_bf, 1024, inw_bf, 1024, xr, 4096, 4096, 1024, 0, nullptr);
    // 2) conv + silu -> xs (overwrites x_bf); v2 row-reuse, grid 512
    conv_silu<<<512, 256, 0, stream>>>(xr, wt, conv_b, xs);
    // 3) x_proj split-K=8, 64-tile
    gemm_s<0, true><<<dim3(2, 32, 8), 256, 0, stream>>>(
        xs, 2048, xpw_bf, 2048, splits, 96, 96, 256, 196608, nullptr);
    reduce96<<<96, 256, 0, stream>>>(splits, xdbl);
    // 4) delta = softplus(xdbl[:,:64] @ dtw^T + b), 64-tile MFMA
    gemm_s<1, false><<<dim3(32, 32, 1), 256, 0, stream>>>(
        xdbl, 96, dtw_bf, 64, xr, 4096, 2048, 64, 0, dtproj_b);
    // 5) chunked scan A -> B -> C (yg in-place over xs)
    scan_chunk<0><<<dim3(8, 32, 2), 256, 0, stream>>>(xr, xs, xdbl, A_log, xr, summ, ssum);
    scan_phaseB<<<256, 256, 0, stream>>>(summ, ssum, A_log);
    scan_chunk<1><<<dim3(8, 32, 2), 256, 0, stream>>>(xr, xs, xdbl, A_log, xr, summ, ssum);
    // 6) out_proj split-K=4, 128x128 tile (weights pre-converted in cvt_front)
    gemm2<0, false><<<dim3(8, 16, 4), 256, 0, stream>>>(
        xs, 2048, opw_bf, 2048, oparts, 1024, 1024, 512, 2097152, nullptr);
    reduce_out<<<1024, 256, 0, stream>>>(oparts, out);
}